// Round 6
// baseline (118.032 us; speedup 1.0000x reference)
//
#include <hip/hip_runtime.h>

// ---------------- problem constants ----------------
#define T_LEN   2048
#define BATCH   2
#define DMODEL  1024
#define NHEAD   16
#define DHEAD   64
#define MROWS   4096          // T*B
#define KDIM    1024
#define NDIM    1024
#define ATT_SC2 (0.125f * 1.44269504088896f)   // SCALE * log2(e), folded into Wq

typedef unsigned short u16;
typedef unsigned int   u32;
typedef u16   u16x8 __attribute__((ext_vector_type(8)));
typedef u16   u16x4 __attribute__((ext_vector_type(4)));
typedef __bf16 bf16x8 __attribute__((ext_vector_type(8)));
typedef float f32x4 __attribute__((ext_vector_type(4)));

__device__ __forceinline__ u16 f2bf(float f) {
  u32 u = __builtin_bit_cast(u32, f);
  u += 0x7fffu + ((u >> 16) & 1u);           // round-to-nearest-even
  return (u16)(u >> 16);
}

__device__ __forceinline__ u16 bfc(float f) {  // compiler cvt (packs to cvt_pk)
  return __builtin_bit_cast(u16, (__bf16)f);
}

__device__ __forceinline__ f32x4 mfma16(u16x8 a, u16x8 b, f32x4 c) {
  return __builtin_amdgcn_mfma_f32_16x16x32_bf16(
      __builtin_bit_cast(bf16x8, a), __builtin_bit_cast(bf16x8, b), c, 0, 0, 0);
}

__device__ __forceinline__ void gload16(const u16* g, u16* l) {
  __builtin_amdgcn_global_load_lds((const __attribute__((address_space(1))) void*)g,
                                   (__attribute__((address_space(3))) void*)l,
                                   16, 0, 0);
}

// ---------------- cast f32 -> bf16 with layout fixes ----------------
// ws (u16): [xbm 4M][Wqkv 3M: rows 0..1023 Wq | 1024..2047 Wk | 2048..3071 Wv]
//           [Wob 1M][Qh 4M][Kh 4M][Vt 4M][Aout 4M]
#define XN 4194304u
__global__ __launch_bounds__(256) void cast_all(
    const float* __restrict__ x,  const float* __restrict__ wk,
    const float* __restrict__ wv, const float* __restrict__ wq,
    const float* __restrict__ wo, u16* __restrict__ ws) {
  size_t i = ((size_t)blockIdx.x * 256 + threadIdx.x) * 4;
  const float* src; size_t soff, doff; float sc = 1.0f;
  if (i < XN) {
    int m = (int)(i >> 10), d = (int)(i & 1023);
    int t = m >> 1, b = m & 1;
    src = x; soff = i;
    doff = ((size_t)(b * 2048 + t) << 10) + d;
  } else {
    size_t off = i - XN;
    int wi = (int)(off >> 20);
    off &= 1048575u;
    int u = (int)(off >> 10), c = (int)(off & 1023);
    src = (wi == 0) ? wk : (wi == 1) ? wv : (wi == 2) ? wq : wo;
    soff = off;
    if (wi == 3) {
      doff = XN + 3u * 1048576u + off;                      // Wob linear
    } else {
      int slot = (wi == 2) ? 0 : (wi == 0) ? 1 : 2;         // Q,K,V pack order
      int up = (u & 15) * 64 + (u >> 4);                    // head-outer perm
      doff = XN + (size_t)slot * 1048576u + ((size_t)up << 10) + c;
      if (wi == 2) sc = ATT_SC2;
    }
  }
  float4 v = *reinterpret_cast<const float4*>(src + soff);
  u16x4 o;
  o.s0 = f2bf(v.x * sc); o.s1 = f2bf(v.y * sc); o.s2 = f2bf(v.z * sc); o.s3 = f2bf(v.w * sc);
  *reinterpret_cast<u16x4*>(ws + doff) = o;
}

// ---------------- QKV GEMM: 256x128 tile, BK=64, per-wave 128x64 ----------------
__global__ __launch_bounds__(256, 2) void gemm_qkv(
    const u16* __restrict__ xbm, const u16* __restrict__ Wqkv,
    u16* __restrict__ Qh, u16* __restrict__ Kh, u16* __restrict__ Vt) {
  __shared__ __align__(16) u16 As[256 * 64];   // 32 KB
  __shared__ __align__(16) u16 Bs[128 * 64];   // 16 KB

  const int tid = threadIdx.x;
  const int l  = tid & 63, w = tid >> 6;
  const int lr = l & 15,  lg = l >> 4;
  const int wm = w >> 1,  wn = w & 1;

  const int blk  = blockIdx.x;
  const int wgid = (blk & 7) * 48 + (blk >> 3);   // bijective (384 % 8 == 0)

  const u16 *A, *W;
  int m0, n0, isV;
  if (wgid < 256) {
    const int bx = wgid >> 4, by = wgid & 15;
    A = xbm; W = Wqkv; m0 = by * 256; n0 = bx * 128; isV = 0;
  } else {
    const int v = wgid - 256;
    const int vby = v >> 5, vbx = v & 31;
    A = Wqkv + (2048u << 10); W = xbm; m0 = vby * 256; n0 = vbx * 128; isV = 1;
  }

  f32x4 acc[8][4];
#pragma unroll
  for (int i = 0; i < 8; ++i)
#pragma unroll
    for (int j = 0; j < 4; ++j) acc[i][j] = (f32x4)(0.0f);

  for (int k0 = 0; k0 < KDIM; k0 += 64) {
#pragma unroll
    for (int i = 0; i < 8; ++i) {
      const int base = i * 256 + w * 64;
      const int p = base + l;
      const int r = p >> 3, c = p & 7;
      gload16(A + (size_t)(m0 + r) * KDIM + k0 + ((c ^ (r & 7)) << 3),
              As + (size_t)base * 8);
    }
#pragma unroll
    for (int i = 0; i < 4; ++i) {
      const int base = i * 256 + w * 64;
      const int p = base + l;
      const int r = p >> 3, c = p & 7;
      gload16(W + (size_t)(n0 + r) * KDIM + k0 + ((c ^ (r & 7)) << 3),
              Bs + (size_t)base * 8);
    }
    __syncthreads();

#pragma unroll
    for (int ks = 0; ks < 2; ++ks) {
      const int cr = ks * 4 + lg;
      u16x8 bf_[4];
#pragma unroll
      for (int ni = 0; ni < 4; ++ni) {
        const int rr = wn * 64 + ni * 16 + lr;
        bf_[ni] = *reinterpret_cast<const u16x8*>(Bs + rr * 64 + ((cr ^ (rr & 7)) << 3));
      }
      __builtin_amdgcn_s_setprio(1);
#pragma unroll
      for (int mi = 0; mi < 8; ++mi) {
        const int rr = wm * 128 + mi * 16 + lr;
        const u16x8 af = *reinterpret_cast<const u16x8*>(
            As + rr * 64 + ((cr ^ (rr & 7)) << 3));
#pragma unroll
        for (int ni = 0; ni < 4; ++ni)
          acc[mi][ni] = mfma16(af, bf_[ni], acc[mi][ni]);
      }
      __builtin_amdgcn_s_setprio(0);
    }
    __syncthreads();
  }

#pragma unroll
  for (int mi = 0; mi < 8; ++mi)
#pragma unroll
    for (int ni = 0; ni < 4; ++ni)
#pragma unroll
      for (int r = 0; r < 4; ++r) {
        const int row = m0 + wm * 128 + mi * 16 + lg * 4 + r;
        const int col = n0 + wn * 64 + ni * 16 + lr;
        const u16 v = bfc(acc[mi][ni][r]);
        if (!isV) {
          const int bb = row >> 11, t = row & 2047;
          const int c = col & 1023, hh = c >> 6, dp = c & 63;
          u16* d = (col < 1024) ? Qh : Kh;
          d[(((size_t)(bb * NHEAD + hh) << 11) + t) * 64 + dp] = v;
        } else {
          const int hh = row >> 6, dp = row & 63;
          const int bb = col >> 11, t = col & 2047;
          Vt[((((size_t)(bb * NHEAD + hh)) * 64 + dp) << 11) + t] = v;
        }
      }
}

// ---------------- O projection: C = A * Wo^T, 128x128 tile ----------------
__global__ __launch_bounds__(256) void gemm_o(
    const u16* __restrict__ A, const u16* __restrict__ W, float* __restrict__ out) {
  __shared__ __align__(16) u16 As[128 * 64];
  __shared__ __align__(16) u16 Bs[128 * 64];

  const int tid = threadIdx.x;
  const int l  = tid & 63, w = tid >> 6;
  const int lr = l & 15,  lg = l >> 4;
  const int wm = w >> 1,  wn = w & 1;
  const int m0 = blockIdx.y * 128;
  const int n0 = blockIdx.x * 128;

  f32x4 acc[4][4];
#pragma unroll
  for (int i = 0; i < 4; ++i)
#pragma unroll
    for (int j = 0; j < 4; ++j) acc[i][j] = (f32x4)(0.0f);

  for (int k0 = 0; k0 < KDIM; k0 += 64) {
#pragma unroll
    for (int i = 0; i < 4; ++i) {
      int p  = i * 256 + tid;
      int r  = p >> 3, cph = p & 7;
      int cl = cph ^ (r & 7);
      u16* ldsA = As + (size_t)(i * 256 + w * 64) * 8;
      u16* ldsB = Bs + (size_t)(i * 256 + w * 64) * 8;
      gload16(A + (size_t)(m0 + r) * KDIM + k0 + cl * 8, ldsA);
      gload16(W + (size_t)(n0 + r) * KDIM + k0 + cl * 8, ldsB);
    }
    __syncthreads();

#pragma unroll
    for (int ks = 0; ks < 2; ++ks) {
      u16x8 af[4], bf_[4];
      const int cr = ks * 4 + lg;
#pragma unroll
      for (int mi = 0; mi < 4; ++mi) {
        int rr = wm * 64 + mi * 16 + lr;
        af[mi] = *reinterpret_cast<const u16x8*>(As + rr * 64 + ((cr ^ (rr & 7)) * 8));
      }
#pragma unroll
      for (int ni = 0; ni < 4; ++ni) {
        int rr = wn * 64 + ni * 16 + lr;
        bf_[ni] = *reinterpret_cast<const u16x8*>(Bs + rr * 64 + ((cr ^ (rr & 7)) * 8));
      }
#pragma unroll
      for (int mi = 0; mi < 4; ++mi)
#pragma unroll
        for (int ni = 0; ni < 4; ++ni)
          acc[mi][ni] = mfma16(af[mi], bf_[ni], acc[mi][ni]);
    }
    __syncthreads();
  }

#pragma unroll
  for (int mi = 0; mi < 4; ++mi)
#pragma unroll
    for (int ni = 0; ni < 4; ++ni)
#pragma unroll
      for (int r = 0; r < 4; ++r) {
        int row = m0 + wm * 64 + mi * 16 + lg * 4 + r;   // b*2048+t
        int col = n0 + wn * 64 + ni * 16 + lr;
        int t = row & 2047, bb = row >> 11;
        out[((size_t)(t * 2 + bb) << 10) + col] = acc[mi][ni][r];
      }
}

// ---------------- causal flash attention v5 ----------------
// 1024 blocks (one 64-row q-block each), kv-step 64, 40KB LDS -> 4 blocks/CU.
// blk: xcd = blk&7, idx = blk>>3 = g*4+m; bh = xcd+8m (XCD-grouped heads);
// qb = balanced pairing so any 4 consecutive idx sum to 66 tile-units.
__global__ __launch_bounds__(256) void attn_fwd(
    const u16* __restrict__ Qh, const u16* __restrict__ Kh,
    const u16* __restrict__ Vt, u16* __restrict__ Aout) {
  __shared__ __align__(16) u16 Ks[2][4096];   // [64 kv][64 d], chunk^(r&7)
  __shared__ __align__(16) u16 Vs[2][4096];   // [64 d][64 kv], chunk^(r&7)
  __shared__ __align__(16) u16 Pl[4][1024];   // per-wave [16 q][64 kv], chunk^(lr&7)

  const int tid = threadIdx.x;
  const int l = tid & 63, w = tid >> 6;
  const int lr = l & 15, lg = l >> 4;
  const int blk = blockIdx.x;
  const int xcd = blk & 7;
  const int idx = blk >> 3;            // 0..127
  const int g = idx >> 2, m = idx & 3;
  const int bh = xcd + 8 * m;
  const int gg = (m & 2) ? ((g + 16) & 31) : g;
  const int qb = (m & 1) ? (31 - gg) : gg;
  const int b = bh >> 4, h = bh & 15;

  const u16* kg = Kh + ((size_t)bh << 17);    // [t][64]
  const u16* vg = Vt + ((size_t)bh << 17);    // [64][2048]

  const u16x8 ones = {0x3F80,0x3F80,0x3F80,0x3F80,0x3F80,0x3F80,0x3F80,0x3F80};

  auto stage = [&](int buf, int kv0) {
#pragma unroll
    for (int j = 0; j < 2; ++j) {
      const int base = (j * 4 + w) * 64;       // chunk base (wave-uniform)
      const int p = base + l;
      const int r = p >> 3, c = p & 7;
      const int cs = ((c ^ (r & 7)) << 3);
      gload16(kg + (size_t)(kv0 + r) * 64 + cs, &Ks[buf][(size_t)base * 8]);
      gload16(vg + ((size_t)r << 11) + kv0 + cs, &Vs[buf][(size_t)base * 8]);
    }
  };

  const int qbase = qb * 64 + w * 16;
  const int qrow = qbase + lr;

  const u16* qptr = Qh + (((size_t)bh << 11) + qrow) * 64 + lg * 8;
  const u16x8 qf0 = *reinterpret_cast<const u16x8*>(qptr);
  const u16x8 qf1 = *reinterpret_cast<const u16x8*>(qptr + 32);

  f32x4 oacc[4];
#pragma unroll
  for (int i = 0; i < 4; ++i) oacc[i] = (f32x4)(0.0f);
  f32x4 sum4 = (f32x4)(0.0f);
  float m_ = -1e30f;

  const int nt = qb + 1;
  stage(0, 0);
  __syncthreads();

  int cur = 0;
  for (int t = 0; t < nt; ++t) {
    const int kv0 = t * 64;
    if (t + 1 < nt) stage(cur ^ 1, kv0 + 64);

    // ---- QK^T swapped: lane holds P[kv=tt*16+lg*4+r][q=lr]
    float p[4][4];
    __builtin_amdgcn_s_setprio(1);
#pragma unroll
    for (int tt = 0; tt < 4; ++tt) {
      const int row = tt * 16 + lr;
      const u16x8 kf0 = *reinterpret_cast<const u16x8*>(
          &Ks[cur][row * 64 + ((lg ^ (row & 7)) << 3)]);
      const u16x8 kf1 = *reinterpret_cast<const u16x8*>(
          &Ks[cur][row * 64 + (((4 + lg) ^ (row & 7)) << 3)]);
      f32x4 sacc = (f32x4)(0.0f);
      sacc = mfma16(kf0, qf0, sacc);
      sacc = mfma16(kf1, qf1, sacc);
#pragma unroll
      for (int r = 0; r < 4; ++r) p[tt][r] = sacc[r];
    }
    __builtin_amdgcn_s_setprio(0);
    if (t == nt - 1) {                         // diagonal tile: causal mask
#pragma unroll
      for (int tt = 0; tt < 4; ++tt)
#pragma unroll
        for (int r = 0; r < 4; ++r) {
          const int kv = kv0 + tt * 16 + lg * 4 + r;
          if (kv > qrow) p[tt][r] = -1e30f;
        }
    }

    // ---- row max: 15 in-lane + 2 shuffles
    float mx = p[0][0];
#pragma unroll
    for (int tt = 0; tt < 4; ++tt)
#pragma unroll
      for (int r = 0; r < 4; ++r) mx = fmaxf(mx, p[tt][r]);
    mx = fmaxf(mx, __shfl_xor(mx, 16, 64));
    mx = fmaxf(mx, __shfl_xor(mx, 32, 64));

    // ---- defer-max rescale (rare)
    if (__any(mx > m_ + 8.0f)) {
      const float mnew = fmaxf(m_, mx);
      const float al = __builtin_amdgcn_exp2f(m_ - mnew);
      m_ = mnew;
#pragma unroll
      for (int r = 0; r < 4; ++r) {
        const float ab = __shfl(al, lg * 4 + r, 64);
        sum4[r] *= ab;
        oacc[0][r] *= ab; oacc[1][r] *= ab; oacc[2][r] *= ab; oacc[3][r] *= ab;
      }
    }

    // ---- P = exp2(S - m)
#pragma unroll
    for (int tt = 0; tt < 4; ++tt)
#pragma unroll
      for (int r = 0; r < 4; ++r)
        p[tt][r] = __builtin_amdgcn_exp2f(p[tt][r] - m_);

    // ---- pack P -> Pl (row q=lr, col kv=tt*16+lg*4+{0..3}, chunk-XOR swz)
#pragma unroll
    for (int tt = 0; tt < 4; ++tt) {
      u16x4 pk;
      pk.s0 = bfc(p[tt][0]); pk.s1 = bfc(p[tt][1]);
      pk.s2 = bfc(p[tt][2]); pk.s3 = bfc(p[tt][3]);
      *reinterpret_cast<u16x4*>(
          &Pl[w][lr * 64 + (((tt * 2 + (lg >> 1)) ^ (lr & 7)) << 3)
                 + ((lg & 1) << 2)]) = pk;
    }

    // ---- PV + MFMA row-sum
    __builtin_amdgcn_s_setprio(1);
#pragma unroll
    for (int kh = 0; kh < 2; ++kh) {
      const u16x8 pa = *reinterpret_cast<const u16x8*>(
          &Pl[w][lr * 64 + (((kh * 4 + lg) ^ (lr & 7)) << 3)]);
      sum4 = mfma16(pa, ones, sum4);           // row-sum in O's C-layout
#pragma unroll
      for (int ni = 0; ni < 4; ++ni) {
        const int dr = ni * 16 + lr;
        const u16x8 vf = *reinterpret_cast<const u16x8*>(
            &Vs[cur][dr * 64 + (((kh * 4 + lg) ^ (dr & 7)) << 3)]);
        oacc[ni] = mfma16(pa, vf, oacc[ni]);
      }
    }
    __builtin_amdgcn_s_setprio(0);

    __syncthreads();   // next tile staged + all waves done with cur
    cur ^= 1;
  }

  // ---- normalize + store
#pragma unroll
  for (int r = 0; r < 4; ++r) {
    const float inv = 1.0f / sum4[r];
    const int q = qbase + lg * 4 + r;
    const size_t rowbase = (((size_t)(b * 2048 + q)) << 10) + h * DHEAD;
#pragma unroll
    for (int ni = 0; ni < 4; ++ni)
      Aout[rowbase + ni * 16 + lr] = bfc(oacc[ni][r] * inv);
  }
}

// ---------------- launch ----------------
extern "C" void kernel_launch(void* const* d_in, const int* in_sizes, int n_in,
                              void* d_out, int out_size, void* d_ws, size_t ws_size,
                              hipStream_t stream) {
  const float* x  = (const float*)d_in[0];
  const float* Wk = (const float*)d_in[1];
  const float* Wv = (const float*)d_in[2];
  const float* Wq = (const float*)d_in[3];
  const float* Wo = (const float*)d_in[4];
  // d_in[5] = mask (causal, known structurally)

  u16* ws   = (u16*)d_ws;
  u16* xbm  = ws;                      // 4M  [b*2048+t][d]
  u16* Wqkv = xbm + 4194304;           // 3M  [Wq|Wk|Wv], head-perm rows
  u16* Wob  = Wqkv + 3145728;          // 1M
  u16* Qh   = Wob + 1048576;           // 4M  [bh][t][64]
  u16* Kh   = Qh  + 4194304;           // 4M  [bh][t][64]
  u16* Vt   = Kh  + 4194304;           // 4M  [bh][64][t]
  u16* Aout = Vt  + 4194304;           // 4M  [b*2048+t][h*64+dp]

  cast_all<<<8192, 256, 0, stream>>>(x, Wk, Wv, Wq, Wo, ws);

  gemm_qkv<<<384, 256, 0, stream>>>(xbm, Wqkv, Qh, Kh, Vt);

  attn_fwd<<<1024, 256, 0, stream>>>(Qh, Kh, Vt, Aout);

  gemm_o<<<dim3(8, 32), 256, 0, stream>>>(Aout, Wob, (float*)d_out);
}